// Round 1
// baseline (921.027 us; speedup 1.0000x reference)
//
#include <hip/hip_runtime.h>
#include <math.h>

#define D        144
#define KCODES   50257
#define NROWS    4096
#define NS       16
#define CHUNK    3142        // ceil(50257/16)
#define BM       64
#define BN       64
#define LDP      68          // padded LDS row (floats); 68*4=272 B, 16B-aligned rows
#define ZQ_OFF   0
#define IDX_OFF  589824
#define LOSS_OFF 593920

// ---------------- kernel 1: fused distance + per-split argmin ----------------
// grid (64 row-tiles, NS splits), 256 threads.
// Replicates reference quantization: d = fl(A_row - fl(2*dot)) in fp32,
// argmin with first-index tie-break.
__global__ __launch_bounds__(256, 2)
void vq_argmin_kernel(const float* __restrict__ z, const float* __restrict__ emb,
                      float* __restrict__ pd, int* __restrict__ pi) {
    __shared__ float zs[D][LDP];   // transposed: zs[k][row_local]
    __shared__ float es[D][LDP];   // transposed: es[k][code_local]
    __shared__ float As[BM];

    const int tid  = threadIdx.x;
    const int bx   = blockIdx.x;        // row tile
    const int sp   = blockIdx.y;        // code split
    const int row0 = bx * BM;
    const int c0   = sp * CHUNK;
    const int c1   = (c0 + CHUNK < KCODES) ? (c0 + CHUNK) : KCODES;

    // stage z tile (transpose into LDS): thread -> row r=tid>>2, part p=tid&3
    {
        const int r = tid >> 2, p = tid & 3;
        const float4* src = (const float4*)(z + (size_t)(row0 + r) * D);
        #pragma unroll
        for (int i = 0; i < 9; ++i) {
            const int j4 = p + 4 * i;          // 0..35
            const float4 v = src[j4];
            zs[4*j4+0][r] = v.x; zs[4*j4+1][r] = v.y;
            zs[4*j4+2][r] = v.z; zs[4*j4+3][r] = v.w;
        }
    }
    __syncthreads();

    // per-row squared norms (fp32; grid-aligned => tie-safe vs reference)
    if (tid < BM) {
        float s = 0.f;
        for (int k = 0; k < D; ++k) { const float t = zs[k][tid]; s = fmaf(t, t, s); }
        As[tid] = s;
    }
    __syncthreads();

    const int tx = tid & 15;   // code dim (4 codes each)
    const int ty = tid >> 4;   // row dim  (4 rows each)

    float Arow[4];
    #pragma unroll
    for (int i = 0; i < 4; ++i) Arow[i] = As[ty*4 + i];

    float bestd[4]; int besti[4];
    #pragma unroll
    for (int i = 0; i < 4; ++i) { bestd[i] = INFINITY; besti[i] = 0x7fffffff; }

    const int ntiles = (c1 - c0 + BN - 1) / BN;
    for (int t = 0; t < ntiles; ++t) {
        const int cb = c0 + t * BN;
        __syncthreads();   // protect es against previous tile's readers
        {
            const int cl = tid >> 2, p = tid & 3;
            int crow = cb + cl; if (crow >= KCODES) crow = KCODES - 1;  // clamp (masked later)
            const float4* src = (const float4*)(emb + (size_t)crow * D);
            #pragma unroll
            for (int i = 0; i < 9; ++i) {
                const int j4 = p + 4 * i;
                const float4 v = src[j4];
                es[4*j4+0][cl] = v.x; es[4*j4+1][cl] = v.y;
                es[4*j4+2][cl] = v.z; es[4*j4+3][cl] = v.w;
            }
        }
        __syncthreads();

        float acc[4][4];
        #pragma unroll
        for (int i = 0; i < 4; ++i)
            #pragma unroll
            for (int j = 0; j < 4; ++j) acc[i][j] = 0.f;

        #pragma unroll 4
        for (int k = 0; k < D; ++k) {
            const float4 a = *(const float4*)&zs[k][ty*4];
            const float4 b = *(const float4*)&es[k][tx*4];
            acc[0][0] = fmaf(a.x, b.x, acc[0][0]);
            acc[0][1] = fmaf(a.x, b.y, acc[0][1]);
            acc[0][2] = fmaf(a.x, b.z, acc[0][2]);
            acc[0][3] = fmaf(a.x, b.w, acc[0][3]);
            acc[1][0] = fmaf(a.y, b.x, acc[1][0]);
            acc[1][1] = fmaf(a.y, b.y, acc[1][1]);
            acc[1][2] = fmaf(a.y, b.z, acc[1][2]);
            acc[1][3] = fmaf(a.y, b.w, acc[1][3]);
            acc[2][0] = fmaf(a.z, b.x, acc[2][0]);
            acc[2][1] = fmaf(a.z, b.y, acc[2][1]);
            acc[2][2] = fmaf(a.z, b.z, acc[2][2]);
            acc[2][3] = fmaf(a.z, b.w, acc[2][3]);
            acc[3][0] = fmaf(a.w, b.x, acc[3][0]);
            acc[3][1] = fmaf(a.w, b.y, acc[3][1]);
            acc[3][2] = fmaf(a.w, b.z, acc[3][2]);
            acc[3][3] = fmaf(a.w, b.w, acc[3][3]);
        }

        #pragma unroll
        for (int j = 0; j < 4; ++j) {
            const int code = cb + tx*4 + j;
            if (code < c1) {
                #pragma unroll
                for (int i = 0; i < 4; ++i) {
                    const float m2 = 2.0f * acc[i][j];   // exact (exponent bump)
                    const float d  = Arow[i] - m2;       // single fp32 rounding, like ref
                    if (d < bestd[i] || (d == bestd[i] && code < besti[i])) {
                        bestd[i] = d; besti[i] = code;
                    }
                }
            }
        }
    }

    // reduce across the 16 lanes (tx) sharing each row
    #pragma unroll
    for (int i = 0; i < 4; ++i) {
        float d = bestd[i]; int idx = besti[i];
        #pragma unroll
        for (int m = 1; m < 16; m <<= 1) {
            const float od = __shfl_xor(d, m, 64);
            const int   oi = __shfl_xor(idx, m, 64);
            if (od < d || (od == d && oi < idx)) { d = od; idx = oi; }
        }
        if (tx == 0) {
            const int r = row0 + ty*4 + i;
            pd[(size_t)sp * NROWS + r] = d;
            pi[(size_t)sp * NROWS + r] = idx;
        }
    }
}

// ------------- kernel 2: cross-split reduce + gather z_q + loss rows ---------
__global__ void vq_finalize_kernel(const float* __restrict__ z,
                                   const float* __restrict__ emb,
                                   const float* __restrict__ pd,
                                   const int*   __restrict__ pi,
                                   float* __restrict__ out,
                                   float* __restrict__ lrow) {
    const int r = blockIdx.x * blockDim.x + threadIdx.x;
    if (r >= NROWS) return;
    float bd = INFINITY; int bi = 0x7fffffff;
    for (int s = 0; s < NS; ++s) {
        const float d = pd[(size_t)s * NROWS + r];
        const int  ix = pi[(size_t)s * NROWS + r];
        if (d < bd || (d == bd && ix < bi)) { bd = d; bi = ix; }
    }
    out[IDX_OFF + r] = (float)bi;   // exact: 50257 < 2^24

    const float4* e4 = (const float4*)(emb + (size_t)bi * D);
    const float4* z4 = (const float4*)(z + (size_t)r * D);
    float4* o4 = (float4*)(out + (size_t)r * D);
    float ls = 0.f;
    #pragma unroll
    for (int j = 0; j < 36; ++j) {
        const float4 e = e4[j], zz = z4[j];
        o4[j] = e;
        const float dx = e.x - zz.x, dy = e.y - zz.y;
        const float dz_ = e.z - zz.z, dw = e.w - zz.w;
        ls += dx*dx + dy*dy + dz_*dz_ + dw*dw;
    }
    lrow[r] = ls;
}

// ---------------------------- kernel 3: final loss ---------------------------
__global__ void vq_loss_kernel(const float* __restrict__ lrow, float* __restrict__ out) {
    __shared__ float sm[256];
    const int tid = threadIdx.x;
    float s = 0.f;
    for (int i = tid; i < NROWS; i += 256) s += lrow[i];
    sm[tid] = s; __syncthreads();
    for (int st = 128; st > 0; st >>= 1) {
        if (tid < st) sm[tid] += sm[tid + st];
        __syncthreads();
    }
    if (tid == 0) out[LOSS_OFF] = sm[0] / 589824.0f;
}

extern "C" void kernel_launch(void* const* d_in, const int* in_sizes, int n_in,
                              void* d_out, int out_size, void* d_ws, size_t ws_size,
                              hipStream_t stream) {
    const float* z   = (const float*)d_in[0];
    const float* emb = (const float*)d_in[1];
    float* out = (float*)d_out;

    float* pd   = (float*)d_ws;                                        // NS*NROWS f32
    int*   pi   = (int*)((char*)d_ws + (size_t)NS * NROWS * 4);        // NS*NROWS i32
    float* lrow = (float*)((char*)d_ws + (size_t)NS * NROWS * 8);      // NROWS f32

    dim3 g1(64, NS);
    vq_argmin_kernel<<<g1, 256, 0, stream>>>(z, emb, pd, pi);
    vq_finalize_kernel<<<16, 256, 0, stream>>>(z, emb, pd, pi, out, lrow);
    vq_loss_kernel<<<1, 256, 0, stream>>>(lrow, out);
}